// Round 6
// baseline (5018.449 us; speedup 1.0000x reference)
//
#include <hip/hip_runtime.h>
#include <hip/hip_bf16.h>

typedef __hip_bfloat16 bf16;
typedef __attribute__((ext_vector_type(8))) short s16x8;   // 8 bf16 (MFMA A/B frag)
typedef __attribute__((ext_vector_type(4))) float f32x4;   // MFMA C/D frag

#define BATCH   64
#define SEQ     256
#define HID     1024
#define GATES   4096
#define NWG     256
#define THREADS 256
#define UNITS   8            // hidden units per WG
#define NCOLS   32           // gate columns per WG (4 gates x 8 units)
#define ROWSTRIDE 2056       // 2048 K + 8 pad elems (LDS bank de-alias)
#define GSTRIDE 33           // gates LDS row stride (+1 pad)
#define BH      (BATCH * HID)

#define H0_SLOTS 4           // layer0 h ring (lets layer0 run ahead)
#define H1_SLOTS 2
#define FLAG_ELEMS ((size_t)6 * BH)            // flags start after h slots (bf16 elems)
#define WS_BYTES  (FLAG_ELEMS * 2 + 256 * 4)   // 786,432 + 1,024 per-WG epoch flags

#define OUT_HN  ((size_t)BATCH * SEQ * HID)
#define OUT_CN  (OUT_HN + 2ull * BATCH * HID)

// fp32 -> bf16 bits, round-to-nearest-even
__device__ __forceinline__ short f2bf(float f) {
    unsigned int u = __builtin_bit_cast(unsigned int, f);
    u = (u + 0x7fffu + ((u >> 16) & 1u)) >> 16;
    return (short)u;
}

// Embedding x-GEMM: plain cached fp32 loads (93% L2/MALL hit measured).
__device__ __forceinline__ void gemm_f32c(const float* xrow, const bf16* s0, const bf16* s1,
                                          f32x4& a0, f32x4& a1)
{
#pragma unroll
    for (int c = 0; c < 4; ++c) {
        f32x4 xv[16];
#pragma unroll
        for (int i = 0; i < 8; ++i) {
            const float* p = xrow + (c * 8 + i) * 32;
            xv[2 * i]     = *(const f32x4*)p;
            xv[2 * i + 1] = *(const f32x4*)(p + 4);
        }
#pragma unroll
        for (int i = 0; i < 8; ++i) {
            const int kk = c * 8 + i;
            s16x8 af;
#pragma unroll
            for (int j = 0; j < 4; ++j) {
                af[j]     = f2bf(xv[2 * i][j]);
                af[4 + j] = f2bf(xv[2 * i + 1][j]);
            }
            s16x8 b0 = *(const s16x8*)(s0 + kk * 32);
            s16x8 b1 = *(const s16x8*)(s1 + kk * 32);
            a0 = __builtin_amdgcn_mfma_f32_16x16x32_bf16(af, b0, a0, 0, 0, 0);
            a1 = __builtin_amdgcn_mfma_f32_16x16x32_bf16(af, b1, a1, 0, 0, 0);
        }
    }
}

// h GEMM over K=1024 with PLAIN CACHED bf16 loads (L1+L2): first toucher per
// XCD pulls each line MALL->L2 (MSHR-merged), the other ~15 co-XCD WGs hit L2.
// Freshness is guaranteed by the caller's post-poll fence(acquire, agent).
// Chunked register staging (4 x 8 loads) mirrors gemm_f32c's proven codegen.
__device__ __forceinline__ void gemm_c(const bf16* xrow, const bf16* s0, const bf16* s1,
                                       f32x4& a0, f32x4& a1)
{
#pragma unroll
    for (int c = 0; c < 4; ++c) {
        s16x8 hv[8];
#pragma unroll
        for (int i = 0; i < 8; ++i)
            hv[i] = *(const s16x8*)(xrow + (c * 8 + i) * 32);
#pragma unroll
        for (int i = 0; i < 8; ++i) {
            const int kk = c * 8 + i;
            s16x8 b0 = *(const s16x8*)(s0 + kk * 32);
            s16x8 b1 = *(const s16x8*)(s1 + kk * 32);
            a0 = __builtin_amdgcn_mfma_f32_16x16x32_bf16(hv[i], b0, a0, 0, 0, 0);
            a1 = __builtin_amdgcn_mfma_f32_16x16x32_bf16(hv[i], b1, a1, 0, 0, 0);
        }
    }
}

// Per-wave poll: lane l watches flags[l], flags[64+l] of a layer's 128 epochs.
// Ends with a compiler memory barrier so no gated load hoists above the poll.
__device__ __forceinline__ void wave_poll(unsigned int* f, int tgt) {
    if (tgt <= 0) return;
    const int l = threadIdx.x & 63;
    unsigned int* p0 = f + l;
    unsigned int* p1 = f + 64 + l;
    for (;;) {
        int a = (int)__hip_atomic_load(p0, __ATOMIC_RELAXED, __HIP_MEMORY_SCOPE_AGENT);
        int b = (int)__hip_atomic_load(p1, __ATOMIC_RELAXED, __HIP_MEMORY_SCOPE_AGENT);
        if (__all((a >= tgt) && (b >= tgt))) break;
        __builtin_amdgcn_s_sleep(1);
    }
    asm volatile("" ::: "memory");
}

__global__ void ws_init(unsigned int* p, int n) {
    for (int i = blockIdx.x * blockDim.x + threadIdx.x; i < n; i += gridDim.x * blockDim.x)
        p[i] = 0u;
}

__global__ void __launch_bounds__(THREADS, 1)
lstm_enc(const int* __restrict__ src, const float* __restrict__ Wemb,
         const float* __restrict__ Wih, const float* __restrict__ Whh,
         const float* __restrict__ bih, const float* __restrict__ bhh,
         float* __restrict__ out, bf16* __restrict__ hbuf)
{
    __shared__ __align__(16) bf16 slab[NCOLS][ROWSTRIDE];   // 131,584 B (persists)
    __shared__ float gates[BATCH][GSTRIDE];                 // 8,448 B
    __shared__ float bias[NCOLS];

    const int wg    = blockIdx.x;
    const int layer = wg >> 7;                 // 0-127: layer0, 128-255: layer1
    const int wgl   = wg & 127;
    const int j0    = wgl * UNITS;
    const int tid   = threadIdx.x;
    const int lane  = tid & 63;
    const int wave  = tid >> 6;
    const int m     = lane & 15;
    const int kq    = (lane >> 4) * 8;
    const int b_a   = wave * 16 + m;           // batch row this lane loads for A

    // ---- weight slab: rows = [i8|f8|g8|o8], K = [W_ih row | W_hh row], fp32->bf16 ----
    for (int r = 0; r < NCOLS; ++r) {
        int g = r >> 3, u = r & 7;
        size_t grow = (size_t)layer * GATES * HID + (size_t)(g * HID + j0 + u) * HID;
        int k = tid * 8;                       // 256 threads x 8 = 2048 exact
        const float* s = (k < HID) ? (Wih + grow + k) : (Whh + grow + (k - HID));
        s16x8 v;
#pragma unroll
        for (int j = 0; j < 8; ++j) v[j] = f2bf(s[j]);
        *(s16x8*)&slab[r][k] = v;
    }
    if (tid < NCOLS) {
        int g = tid >> 3, u = tid & 7;
        int off = layer * GATES + g * HID + j0 + u;
        bias[tid] = bih[off] + bhh[off];
    }
    __syncthreads();

    // kill stale L1/L2 lines from previous replays before first cached h read
    __builtin_amdgcn_fence(__ATOMIC_ACQUIRE, "agent");

    bf16* h0 = hbuf;                           // [4][B][H] ring
    bf16* h1 = hbuf + H0_SLOTS * BH;           // [2][B][H] ring
    unsigned int* flags = (unsigned int*)(hbuf + FLAG_ELEMS);  // per-WG epoch counters
    unsigned int* f0 = flags;                  // layer0 epochs [0..127]
    unsigned int* f1 = flags + 128;            // layer1 epochs [0..127]

    // epilogue mapping: thread -> (bb = tid>>2, u0 = 2*(tid&3)); c-state in registers
    const int bb = tid >> 2;
    const int u0 = (tid & 3) * 2;
    float c_lo = 0.f, c_hi = 0.f;

    int sv = (layer == 0) ? src[b_a * SEQ] : 0;   // prefetched src token

    for (int t = 0; t < SEQ; ++t) {
        f32x4 acc0 = {0.f, 0.f, 0.f, 0.f};
        f32x4 acc1 = {0.f, 0.f, 0.f, 0.f};

        if (layer == 0) {
            // ---- x @ W_ih^T from embedding (cached fp32): no cross-WG dep ----
            const float* xF = Wemb + (size_t)sv * HID + kq;
            if (t + 1 < SEQ) sv = src[b_a * SEQ + t + 1];
            gemm_f32c(xF, &slab[m][kq], &slab[16 + m][kq], acc0, acc1);
            // own layer done t-1 -> h0[t-1] at MALL
            wave_poll(f0, t);
            if (t >= 1) {
                // invalidate L2 AFTER the poll, BEFORE the cached h read:
                // every h line fetched after this is MALL-fresh (needed version)
                __builtin_amdgcn_fence(__ATOMIC_ACQUIRE, "agent");
                gemm_c(h0 + (size_t)((t - 1) & (H0_SLOTS - 1)) * BH + b_a * HID + kq,
                       &slab[m][HID + kq], &slab[16 + m][HID + kq], acc0, acc1);
            }
            // ring protect: L1 done t-4 before we overwrite h0 slot t&3
            wave_poll(f1, t - 3);
        } else {
            // L0 runs ahead -> usually pre-satisfied
            wave_poll(f0, t + 1);
            // single per-step fence covers BOTH h0[t] and h1[t-1] reads:
            // h1 addrs are untouched between fence and the post-f1-poll read,
            // so no stale line can be re-cached in the window.
            __builtin_amdgcn_fence(__ATOMIC_ACQUIRE, "agent");
            gemm_c(h0 + (size_t)(t & (H0_SLOTS - 1)) * BH + b_a * HID + kq,
                   &slab[m][kq], &slab[16 + m][kq], acc0, acc1);
            // own layer done t-1 -> h1[t-1] at MALL (also ring-protects slot t&1)
            wave_poll(f1, t);
            if (t >= 1)
                gemm_c(h1 + (size_t)((t - 1) & (H1_SLOTS - 1)) * BH + b_a * HID + kq,
                       &slab[m][HID + kq], &slab[16 + m][HID + kq], acc0, acc1);
        }

        // C/D layout: col = lane&15, row = (lane>>4)*4 + r  (verified m89/m91)
        const int rowg = wave * 16 + (lane >> 4) * 4;
#pragma unroll
        for (int r = 0; r < 4; ++r) {
            gates[rowg + r][m]      = acc0[r];
            gates[rowg + r][16 + m] = acc1[r];
        }
        __syncthreads();   // #1: gates complete

        // ---- epilogue: 2 adjacent units per thread, c-state in registers ----
        float gi0 = gates[bb][u0]      + bias[u0];
        float gi1 = gates[bb][u0 + 1]  + bias[u0 + 1];
        float gf0 = gates[bb][u0 + 8]  + bias[u0 + 8];
        float gf1 = gates[bb][u0 + 9]  + bias[u0 + 9];
        float gg0 = gates[bb][u0 + 16] + bias[u0 + 16];
        float gg1 = gates[bb][u0 + 17] + bias[u0 + 17];
        float go0 = gates[bb][u0 + 24] + bias[u0 + 24];
        float go1 = gates[bb][u0 + 25] + bias[u0 + 25];
        float si0 = 1.f / (1.f + __expf(-gi0)), si1 = 1.f / (1.f + __expf(-gi1));
        float sf0 = 1.f / (1.f + __expf(-gf0)), sf1 = 1.f / (1.f + __expf(-gf1));
        float so0 = 1.f / (1.f + __expf(-go0)), so1 = 1.f / (1.f + __expf(-go1));
        float tg0 = tanhf(gg0), tg1 = tanhf(gg1);
        c_lo = sf0 * c_lo + si0 * tg0;
        c_hi = sf1 * c_hi + si1 * tg1;
        float h_lo = so0 * tanhf(c_lo);
        float h_hi = so1 * tanhf(c_hi);

        // h store: agent-scope write-through -> lands at MALL (ring stays resident)
        bf16* hw = ((layer == 0) ? h0 + (size_t)(t & (H0_SLOTS - 1)) * BH
                                 : h1 + (size_t)(t & (H1_SLOTS - 1)) * BH);
        unsigned int hp = (unsigned int)(unsigned short)f2bf(h_lo) |
                          ((unsigned int)(unsigned short)f2bf(h_hi) << 16);
        __hip_atomic_store((unsigned int*)(hw + bb * HID + j0 + u0), hp,
                           __ATOMIC_RELAXED, __HIP_MEMORY_SCOPE_AGENT);

        __syncthreads();   // #2: drains vmcnt(0) -> h stores at coherent point
        asm volatile("" ::: "memory");
        if (tid == 0)      // per-WG epoch store
            __hip_atomic_store(flags + wg, (unsigned int)(t + 1),
                               __ATOMIC_RELAXED, __HIP_MEMORY_SCOPE_AGENT);

        // ---- post-flag final outputs: off the recurrence critical path ----
        if (layer == 1)
            *(float2*)(out + ((size_t)bb * SEQ + t) * HID + j0 + u0) = make_float2(h_lo, h_hi);
        if (t == SEQ - 1) {
            size_t o = ((size_t)layer * BATCH + bb) * HID + j0 + u0;
            *(float2*)(out + OUT_HN + o) = make_float2(h_lo, h_hi);
            *(float2*)(out + OUT_CN + o) = make_float2(c_lo, c_hi);
        }
    }
}

extern "C" void kernel_launch(void* const* d_in, const int* in_sizes, int n_in,
                              void* d_out, int out_size, void* d_ws, size_t ws_size,
                              hipStream_t stream) {
    const int*   src  = (const int*)d_in[0];
    const float* emb  = (const float*)d_in[1];
    const float* W_ih = (const float*)d_in[2];
    const float* W_hh = (const float*)d_in[3];
    const float* b_ih = (const float*)d_in[4];
    const float* b_hh = (const float*)d_in[5];
    float* out  = (float*)d_out;
    bf16*  hbuf = (bf16*)d_ws;                 // uses 787,456 B

    // zero rings + flag words (ws is re-poisoned 0xAA before every replay)
    unsigned int* wsp = (unsigned int*)d_ws;
    int n = (int)(WS_BYTES / 4);
    ws_init<<<256, 256, 0, stream>>>(wsp, n);

    void* args[] = {&src, &emb, &W_ih, &W_hh, &b_ih, &b_hh, &out, &hbuf};
    hipLaunchCooperativeKernel((void*)lstm_enc, dim3(NWG), dim3(THREADS),
                               args, 0, stream);
}

// Round 7
// 3920.688 us; speedup vs baseline: 1.2800x; 1.2800x over previous
//
#include <hip/hip_runtime.h>
#include <hip/hip_bf16.h>

typedef __hip_bfloat16 bf16;
typedef __attribute__((ext_vector_type(8))) short s16x8;   // 8 bf16 (MFMA A/B frag)
typedef __attribute__((ext_vector_type(4))) float f32x4;   // MFMA C/D frag
typedef __attribute__((ext_vector_type(4))) int   i32x4;

#define BATCH   64
#define SEQ     256
#define HID     1024
#define GATES   4096
#define NWG     256
#define THREADS 256
#define UNITS   8
#define NCOLS   32
#define ROWSTRIDE 2056
#define GSTRIDE 33
#define BH      (BATCH * HID)

#define H0_SLOTS 4
#define H1_SLOTS 2
// ---- ws byte layout ----
#define FLAGS_OFF  786432ull                 // after h rings (4+2)*BH*2
#define META_OFF   (FLAGS_OFF + 1024)        // [0..7] L0-per-xcd count, [8..15] L1, [16] total
#define ARR_OFF    (FLAGS_OFF + 2048)        // 24 arrive counters, 128 B apart
#define STAGE0_OFF 1048576ull                // 8 xcd x 4 slots x 128 KB = 4 MB
#define STAGE1_OFF (STAGE0_OFF + 8ull * H0_SLOTS * BH * 2)
#define WS_NEED    (STAGE1_OFF + 8ull * H1_SLOTS * BH * 2)   // 7,340,032 B

#define OUT_HN  ((size_t)BATCH * SEQ * HID)
#define OUT_CN  (OUT_HN + 2ull * BATCH * HID)

__device__ __forceinline__ short f2bf(float f) {   // rne fp32->bf16
    unsigned int u = __builtin_bit_cast(unsigned int, f);
    u = (u + 0x7fffu + ((u >> 16) & 1u)) >> 16;
    return (short)u;
}

// 16B coherent-point load (bypass L1+L2)
__device__ __forceinline__ s16x8 ldg16(const bf16* p) {
    i32x4 r;
    asm volatile("global_load_dwordx4 %0, %1, off sc0 sc1" : "=v"(r) : "v"(p));
    return __builtin_bit_cast(s16x8, r);
}

// ---- GEMM over K=1024: pipelined 32x16B loads, counted vmcnt, rule-#18 fences.
// gemm_bt: sc0 sc1 (coherent point; fallback path). gemm_s: sc0 (L1-bypass,
// L2-visible -> reads the XCD-local staged copy; guaranteed dirty-L2 hit).
#define GLD(i, OFF, CF) asm volatile("global_load_dwordx4 %0, %1, off offset:" OFF " " CF \
                                     : "=v"(h[i]) : "v"(xrow));
#define MM8(B0) \
    _Pragma("unroll") \
    for (int kk = (B0); kk < (B0) + 8; ++kk) { \
        s16x8 b0 = *(const s16x8*)(s0 + kk * 32); \
        s16x8 b1 = *(const s16x8*)(s1 + kk * 32); \
        s16x8 av = __builtin_bit_cast(s16x8, h[kk]); \
        a0 = __builtin_amdgcn_mfma_f32_16x16x32_bf16(av, b0, a0, 0, 0, 0); \
        a1 = __builtin_amdgcn_mfma_f32_16x16x32_bf16(av, b1, a1, 0, 0, 0); \
    }
#define GEMM_FN(NAME, CF) \
__device__ __forceinline__ void NAME(const bf16* xrow, const bf16* s0, const bf16* s1, \
                                     f32x4& a0, f32x4& a1) \
{ \
    i32x4 h[32]; \
    GLD(0,"0",CF)    GLD(1,"64",CF)   GLD(2,"128",CF)  GLD(3,"192",CF) \
    GLD(4,"256",CF)  GLD(5,"320",CF)  GLD(6,"384",CF)  GLD(7,"448",CF) \
    GLD(8,"512",CF)  GLD(9,"576",CF)  GLD(10,"640",CF) GLD(11,"704",CF) \
    GLD(12,"768",CF) GLD(13,"832",CF) GLD(14,"896",CF) GLD(15,"960",CF) \
    GLD(16,"1024",CF) GLD(17,"1088",CF) GLD(18,"1152",CF) GLD(19,"1216",CF) \
    GLD(20,"1280",CF) GLD(21,"1344",CF) GLD(22,"1408",CF) GLD(23,"1472",CF) \
    asm volatile("s_waitcnt vmcnt(16)"); __builtin_amdgcn_sched_barrier(0); \
    MM8(0) \
    GLD(24,"1536",CF) GLD(25,"1600",CF) GLD(26,"1664",CF) GLD(27,"1728",CF) \
    GLD(28,"1792",CF) GLD(29,"1856",CF) GLD(30,"1920",CF) GLD(31,"1984",CF) \
    asm volatile("s_waitcnt vmcnt(16)"); __builtin_amdgcn_sched_barrier(0); \
    MM8(8) \
    asm volatile("s_waitcnt vmcnt(8)");  __builtin_amdgcn_sched_barrier(0); \
    MM8(16) \
    asm volatile("s_waitcnt vmcnt(0)");  __builtin_amdgcn_sched_barrier(0); \
    MM8(24) \
}
GEMM_FN(gemm_bt, "sc0 sc1")
GEMM_FN(gemm_s,  "sc0")

// Embedding x-GEMM: plain cached fp32 loads.
__device__ __forceinline__ void gemm_f32c(const float* xrow, const bf16* s0, const bf16* s1,
                                          f32x4& a0, f32x4& a1)
{
#pragma unroll
    for (int c = 0; c < 4; ++c) {
        f32x4 xv[16];
#pragma unroll
        for (int i = 0; i < 8; ++i) {
            const float* p = xrow + (c * 8 + i) * 32;
            xv[2 * i]     = *(const f32x4*)p;
            xv[2 * i + 1] = *(const f32x4*)(p + 4);
        }
#pragma unroll
        for (int i = 0; i < 8; ++i) {
            const int kk = c * 8 + i;
            s16x8 af;
#pragma unroll
            for (int j = 0; j < 4; ++j) {
                af[j]     = f2bf(xv[2 * i][j]);
                af[4 + j] = f2bf(xv[2 * i + 1][j]);
            }
            s16x8 b0 = *(const s16x8*)(s0 + kk * 32);
            s16x8 b1 = *(const s16x8*)(s1 + kk * 32);
            a0 = __builtin_amdgcn_mfma_f32_16x16x32_bf16(af, b0, a0, 0, 0, 0);
            a1 = __builtin_amdgcn_mfma_f32_16x16x32_bf16(af, b1, a1, 0, 0, 0);
        }
    }
}

// wave0-only global flag poll (lane l watches flags[l], flags[64+l]); barrier.
__device__ __forceinline__ void poll_flags(unsigned int* f, int tgt, int wave) {
    if (wave == 0 && tgt > 0) {
        const int l = threadIdx.x & 63;
        unsigned int* p0 = f + l;
        unsigned int* p1 = f + 64 + l;
        for (;;) {
            int a = (int)__hip_atomic_load(p0, __ATOMIC_RELAXED, __HIP_MEMORY_SCOPE_AGENT);
            int b = (int)__hip_atomic_load(p1, __ATOMIC_RELAXED, __HIP_MEMORY_SCOPE_AGENT);
            if (__all((a >= tgt) && (b >= tgt))) break;
            __builtin_amdgcn_s_sleep(1);
        }
    }
    __syncthreads();
    asm volatile("" ::: "memory");
}

// Stage a row-slice [r0,r1) of a 64x1024 bf16 slot: bypass-read from the ring
// (MALL truth), plain write-back store into the XCD-private stage buffer.
__device__ __forceinline__ void stage_copy(const bf16* src, bf16* dst, int r0, int r1) {
    const int tid = threadIdx.x;
    const int chunks = (r1 - r0) * 128;            // 16B chunks
    const char* s = (const char*)src + r0 * 2048;
    char* d = (char*)dst + r0 * 2048;
    for (int i = tid; i < chunks; i += 1024) {
        s16x8 v0, v1, v2, v3;
        const int i1 = i + 256, i2 = i + 512, i3 = i + 768;
        v0 = ldg16((const bf16*)(s + (size_t)i * 16));
        if (i1 < chunks) v1 = ldg16((const bf16*)(s + (size_t)i1 * 16));
        if (i2 < chunks) v2 = ldg16((const bf16*)(s + (size_t)i2 * 16));
        if (i3 < chunks) v3 = ldg16((const bf16*)(s + (size_t)i3 * 16));
        asm volatile("s_waitcnt vmcnt(0)");
        __builtin_amdgcn_sched_barrier(0);
        *(s16x8*)(d + (size_t)i * 16) = v0;
        if (i1 < chunks) *(s16x8*)(d + (size_t)i1 * 16) = v1;
        if (i2 < chunks) *(s16x8*)(d + (size_t)i2 * 16) = v2;
        if (i3 < chunks) *(s16x8*)(d + (size_t)i3 * 16) = v3;
    }
}

// stage slice -> drain (barrier) -> arrive -> wait all same-(layer,xcd) WGs
__device__ __forceinline__ void stage_sync(const bf16* src, bf16* dst, int r0, int r1,
                                           unsigned int* arr, int tgt) {
    stage_copy(src, dst, r0, r1);
    __syncthreads();                               // drains vmcnt: stores in local L2
    if (threadIdx.x == 0) {
        __hip_atomic_fetch_add(arr, 1u, __ATOMIC_RELAXED, __HIP_MEMORY_SCOPE_AGENT);
        while ((int)__hip_atomic_load(arr, __ATOMIC_RELAXED, __HIP_MEMORY_SCOPE_AGENT) < tgt)
            __builtin_amdgcn_s_sleep(1);
    }
    __syncthreads();
    asm volatile("" ::: "memory");
}

__global__ void ws_init(unsigned int* p, int n) {
    for (int i = blockIdx.x * blockDim.x + threadIdx.x; i < n; i += gridDim.x * blockDim.x)
        p[i] = 0u;
}

__global__ void __launch_bounds__(THREADS, 1)
lstm_enc(const int* __restrict__ src, const float* __restrict__ Wemb,
         const float* __restrict__ Wih, const float* __restrict__ Whh,
         const float* __restrict__ bih, const float* __restrict__ bhh,
         float* __restrict__ out, bf16* __restrict__ hbuf, int stage_on)
{
    __shared__ __align__(16) bf16 slab[NCOLS][ROWSTRIDE];
    __shared__ float gates[BATCH][GSTRIDE];
    __shared__ float bias[NCOLS];
    __shared__ int sh_rank, sh_n;

    const int wg    = blockIdx.x;
    const int layer = wg >> 7;
    const int wgl   = wg & 127;
    const int j0    = wgl * UNITS;
    const int tid   = threadIdx.x;
    const int lane  = tid & 63;
    const int wave  = tid >> 6;
    const int m     = lane & 15;
    const int kq    = (lane >> 4) * 8;
    const int b_a   = wave * 16 + m;

    // ---- weight slab ----
    for (int r = 0; r < NCOLS; ++r) {
        int g = r >> 3, u = r & 7;
        size_t grow = (size_t)layer * GATES * HID + (size_t)(g * HID + j0 + u) * HID;
        int k = tid * 8;
        const float* s = (k < HID) ? (Wih + grow + k) : (Whh + grow + (k - HID));
        s16x8 v;
#pragma unroll
        for (int j = 0; j < 8; ++j) v[j] = f2bf(s[j]);
        *(s16x8*)&slab[r][k] = v;
    }
    if (tid < NCOLS) {
        int g = tid >> 3, u = tid & 7;
        int off = layer * GATES + g * HID + j0 + u;
        bias[tid] = bih[off] + bhh[off];
    }

    char* wsb = (char*)hbuf;
    bf16* h0 = hbuf;                               // [4][B][H] ring
    bf16* h1 = hbuf + H0_SLOTS * BH;               // [2][B][H] ring
    unsigned int* flags = (unsigned int*)(wsb + FLAGS_OFF);
    unsigned int* f0 = flags;
    unsigned int* f1 = flags + 128;
    unsigned int* meta = (unsigned int*)(wsb + META_OFF);

    // ---- per-(layer,XCD) registration: true die id + runtime rank ----
    unsigned int xcc = 0;
    int r0s = 0, r1s = 0;
    if (stage_on) {
        unsigned int xr;
        asm volatile("s_getreg_b32 %0, hwreg(HW_REG_XCC_ID)" : "=s"(xr));
        xcc = xr & 7u;
        if (tid == 0) {
            unsigned int* reg = meta + layer * 8 + xcc;
            sh_rank = (int)__hip_atomic_fetch_add(reg, 1u, __ATOMIC_RELAXED, __HIP_MEMORY_SCOPE_AGENT);
            __hip_atomic_fetch_add(meta + 16, 1u, __ATOMIC_RELAXED, __HIP_MEMORY_SCOPE_AGENT);
            while ((int)__hip_atomic_load(meta + 16, __ATOMIC_RELAXED, __HIP_MEMORY_SCOPE_AGENT) < NWG)
                __builtin_amdgcn_s_sleep(1);
            sh_n = (int)__hip_atomic_load(reg, __ATOMIC_RELAXED, __HIP_MEMORY_SCOPE_AGENT);
        }
        __syncthreads();
        const int rank = sh_rank, n = sh_n;
        r0s = (BATCH * rank) / n;
        r1s = (BATCH * (rank + 1)) / n;
    } else {
        __syncthreads();
    }
    const int nG = stage_on ? sh_n : 0;
    unsigned int* arrA = (unsigned int*)(wsb + ARR_OFF) + xcc * 32;
    unsigned int* arrB = arrA + 8 * 32;
    unsigned int* arrC = arrA + 16 * 32;
    bf16* stage0 = (bf16*)(wsb + STAGE0_OFF) + (size_t)xcc * H0_SLOTS * BH;
    bf16* stage1 = (bf16*)(wsb + STAGE1_OFF) + (size_t)xcc * H1_SLOTS * BH;

    const int bb = tid >> 2;
    const int u0 = (tid & 3) * 2;
    float c_lo = 0.f, c_hi = 0.f;

    int sv = (layer == 0) ? src[b_a * SEQ] : 0;

    for (int t = 0; t < SEQ; ++t) {
        f32x4 acc0 = {0.f, 0.f, 0.f, 0.f};
        f32x4 acc1 = {0.f, 0.f, 0.f, 0.f};

        if (layer == 0) {
            const float* xF = Wemb + (size_t)sv * HID + kq;
            if (t + 1 < SEQ) sv = src[b_a * SEQ + t + 1];
            gemm_f32c(xF, &slab[m][kq], &slab[16 + m][kq], acc0, acc1);
            poll_flags(f0, t, wave);                       // own layer done t-1
            if (t >= 1) {
                const bf16* rs = h0 + (size_t)((t - 1) & 3) * BH;
                if (stage_on) {
                    bf16* ds = stage0 + (size_t)((t - 1) & 3) * BH;
                    stage_sync(rs, ds, r0s, r1s, arrA, nG * t);
                    gemm_s(ds + b_a * HID + kq,
                           &slab[m][HID + kq], &slab[16 + m][HID + kq], acc0, acc1);
                } else {
                    gemm_bt(rs + b_a * HID + kq,
                            &slab[m][HID + kq], &slab[16 + m][HID + kq], acc0, acc1);
                }
            }
            poll_flags(f1, t - 3, wave);                   // h0 ring protect
        } else {
            poll_flags(f0, t + 1, wave);                   // L0 done t -> h0[t] ready
            {
                const bf16* rs = h0 + (size_t)(t & 3) * BH;
                if (stage_on) {
                    bf16* ds = stage0 + (size_t)(t & 3) * BH;
                    stage_sync(rs, ds, r0s, r1s, arrB, nG * (t + 1));
                    gemm_s(ds + b_a * HID + kq,
                           &slab[m][kq], &slab[16 + m][kq], acc0, acc1);
                } else {
                    gemm_bt(rs + b_a * HID + kq,
                            &slab[m][kq], &slab[16 + m][kq], acc0, acc1);
                }
            }
            poll_flags(f1, t, wave);                       // own layer done t-1
            if (t >= 1) {
                const bf16* rs = h1 + (size_t)((t - 1) & 1) * BH;
                if (stage_on) {
                    bf16* ds = stage1 + (size_t)((t - 1) & 1) * BH;
                    stage_sync(rs, ds, r0s, r1s, arrC, nG * t);
                    gemm_s(ds + b_a * HID + kq,
                           &slab[m][HID + kq], &slab[16 + m][HID + kq], acc0, acc1);
                } else {
                    gemm_bt(rs + b_a * HID + kq,
                            &slab[m][HID + kq], &slab[16 + m][HID + kq], acc0, acc1);
                }
            }
        }

        // C/D layout: col = lane&15, row = (lane>>4)*4 + r (verified m89/m91)
        const int rowg = wave * 16 + (lane >> 4) * 4;
#pragma unroll
        for (int r = 0; r < 4; ++r) {
            gates[rowg + r][m]      = acc0[r];
            gates[rowg + r][16 + m] = acc1[r];
        }
        __syncthreads();

        // ---- epilogue ----
        float gi0 = gates[bb][u0]      + bias[u0];
        float gi1 = gates[bb][u0 + 1]  + bias[u0 + 1];
        float gf0 = gates[bb][u0 + 8]  + bias[u0 + 8];
        float gf1 = gates[bb][u0 + 9]  + bias[u0 + 9];
        float gg0 = gates[bb][u0 + 16] + bias[u0 + 16];
        float gg1 = gates[bb][u0 + 17] + bias[u0 + 17];
        float go0 = gates[bb][u0 + 24] + bias[u0 + 24];
        float go1 = gates[bb][u0 + 25] + bias[u0 + 25];
        float si0 = 1.f / (1.f + __expf(-gi0)), si1 = 1.f / (1.f + __expf(-gi1));
        float sf0 = 1.f / (1.f + __expf(-gf0)), sf1 = 1.f / (1.f + __expf(-gf1));
        float so0 = 1.f / (1.f + __expf(-go0)), so1 = 1.f / (1.f + __expf(-go1));
        float tg0 = tanhf(gg0), tg1 = tanhf(gg1);
        c_lo = sf0 * c_lo + si0 * tg0;
        c_hi = sf1 * c_hi + si1 * tg1;
        float h_lo = so0 * tanhf(c_lo);
        float h_hi = so1 * tanhf(c_hi);

        bf16* hw = ((layer == 0) ? h0 + (size_t)(t & 3) * BH
                                 : h1 + (size_t)(t & 1) * BH);
        unsigned int hp = (unsigned int)(unsigned short)f2bf(h_lo) |
                          ((unsigned int)(unsigned short)f2bf(h_hi) << 16);
        __hip_atomic_store((unsigned int*)(hw + bb * HID + j0 + u0), hp,
                           __ATOMIC_RELAXED, __HIP_MEMORY_SCOPE_AGENT);

        __syncthreads();   // drains vmcnt(0): h stores at coherent point
        asm volatile("" ::: "memory");
        if (tid == 0)
            __hip_atomic_store(flags + wg, (unsigned int)(t + 1),
                               __ATOMIC_RELAXED, __HIP_MEMORY_SCOPE_AGENT);

        // post-flag final outputs (off the recurrence critical path)
        if (layer == 1)
            *(float2*)(out + ((size_t)bb * SEQ + t) * HID + j0 + u0) = make_float2(h_lo, h_hi);
        if (t == SEQ - 1) {
            size_t o = ((size_t)layer * BATCH + bb) * HID + j0 + u0;
            *(float2*)(out + OUT_HN + o) = make_float2(h_lo, h_hi);
            *(float2*)(out + OUT_CN + o) = make_float2(c_lo, c_hi);
        }
    }
}

extern "C" void kernel_launch(void* const* d_in, const int* in_sizes, int n_in,
                              void* d_out, int out_size, void* d_ws, size_t ws_size,
                              hipStream_t stream) {
    const int*   src  = (const int*)d_in[0];
    const float* emb  = (const float*)d_in[1];
    const float* W_ih = (const float*)d_in[2];
    const float* W_hh = (const float*)d_in[3];
    const float* b_ih = (const float*)d_in[4];
    const float* b_hh = (const float*)d_in[5];
    float* out  = (float*)d_out;
    bf16*  hbuf = (bf16*)d_ws;

    // zero flags + meta + arrive counters (stage buffers need no init:
    // every staged byte is written before read within the same step)
    unsigned int* wsp = (unsigned int*)((char*)d_ws + FLAGS_OFF);
    ws_init<<<8, 256, 0, stream>>>(wsp, 8192 / 4);

    int stage_on = (ws_size >= (size_t)WS_NEED) ? 1 : 0;

    void* args[] = {&src, &emb, &W_ih, &W_hh, &b_ih, &b_hh, &out, &hbuf, &stage_on};
    hipLaunchCooperativeKernel((void*)lstm_enc, dim3(NWG), dim3(THREADS),
                               args, 0, stream);
}

// Round 8
// 3771.691 us; speedup vs baseline: 1.3306x; 1.0395x over previous
//
#include <hip/hip_runtime.h>
#include <hip/hip_bf16.h>

typedef __hip_bfloat16 bf16;
typedef __attribute__((ext_vector_type(8))) short s16x8;   // 8 bf16 (MFMA A/B frag)
typedef __attribute__((ext_vector_type(4))) float f32x4;   // MFMA C/D frag
typedef __attribute__((ext_vector_type(4))) int   i32x4;

#define BATCH   64
#define SEQ     256
#define HID     1024
#define GATES   4096
#define NWG     256
#define THREADS 256
#define UNITS   8
#define NCOLS   32
#define ROWSTRIDE 2056       // 2048 K + 8 pad elems (LDS bank de-alias)
#define BH      (BATCH * HID)

#define H0_SLOTS 8           // slack-7 ring: L0 free-runs ahead, ring poll rarely binds
#define H1_SLOTS 2
#define FLAGS_OFF ((size_t)(H0_SLOTS + H1_SLOTS) * BH * 2)   // 1,310,720
// flags: [layer][wave][wgl] -> 2 x 512 words = 4 KB. Wave-w consumers only read
// rows 16w..16w+15 == wave-w producers' rows: per-wave chains are independent.

#define OUT_HN  ((size_t)BATCH * SEQ * HID)
#define OUT_CN  (OUT_HN + 2ull * BATCH * HID)

__device__ __forceinline__ short f2bf(float f) {   // rne fp32->bf16
    unsigned int u = __builtin_bit_cast(unsigned int, f);
    u = (u + 0x7fffu + ((u >> 16) & 1u)) >> 16;
    return (short)u;
}

// ---- h GEMM over K=1024: coherent-point loads (sc0 sc1), single base +
// immediate offsets, counted-vmcnt pipeline, sched_barrier (rule #18). ----
#define GLD(i, OFF) asm volatile("global_load_dwordx4 %0, %1, off offset:" OFF " sc0 sc1" \
                                 : "=v"(h[i]) : "v"(xrow));
#define MM8(B0) \
    _Pragma("unroll") \
    for (int kk = (B0); kk < (B0) + 8; ++kk) { \
        s16x8 b0 = *(const s16x8*)(s0 + kk * 32); \
        s16x8 b1 = *(const s16x8*)(s1 + kk * 32); \
        s16x8 av = __builtin_bit_cast(s16x8, h[kk]); \
        a0 = __builtin_amdgcn_mfma_f32_16x16x32_bf16(av, b0, a0, 0, 0, 0); \
        a1 = __builtin_amdgcn_mfma_f32_16x16x32_bf16(av, b1, a1, 0, 0, 0); \
    }
__device__ __forceinline__ void gemm_bt(const bf16* xrow, const bf16* s0, const bf16* s1,
                                        f32x4& a0, f32x4& a1)
{
    i32x4 h[32];
    GLD(0,"0")    GLD(1,"64")   GLD(2,"128")  GLD(3,"192")
    GLD(4,"256")  GLD(5,"320")  GLD(6,"384")  GLD(7,"448")
    GLD(8,"512")  GLD(9,"576")  GLD(10,"640") GLD(11,"704")
    GLD(12,"768") GLD(13,"832") GLD(14,"896") GLD(15,"960")
    GLD(16,"1024") GLD(17,"1088") GLD(18,"1152") GLD(19,"1216")
    GLD(20,"1280") GLD(21,"1344") GLD(22,"1408") GLD(23,"1472")
    asm volatile("s_waitcnt vmcnt(16)"); __builtin_amdgcn_sched_barrier(0);
    MM8(0)
    GLD(24,"1536") GLD(25,"1600") GLD(26,"1664") GLD(27,"1728")
    GLD(28,"1792") GLD(29,"1856") GLD(30,"1920") GLD(31,"1984")
    asm volatile("s_waitcnt vmcnt(16)"); __builtin_amdgcn_sched_barrier(0);
    MM8(8)
    asm volatile("s_waitcnt vmcnt(8)");  __builtin_amdgcn_sched_barrier(0);
    MM8(16)
    asm volatile("s_waitcnt vmcnt(0)");  __builtin_amdgcn_sched_barrier(0);
    MM8(24)
}

// Embedding x-GEMM: plain cached fp32 loads (L2/MALL shared; ~93% hit).
__device__ __forceinline__ void gemm_f32c(const float* xrow, const bf16* s0, const bf16* s1,
                                          f32x4& a0, f32x4& a1)
{
#pragma unroll
    for (int c = 0; c < 4; ++c) {
        f32x4 xv[16];
#pragma unroll
        for (int i = 0; i < 8; ++i) {
            const float* p = xrow + (c * 8 + i) * 32;
            xv[2 * i]     = *(const f32x4*)p;
            xv[2 * i + 1] = *(const f32x4*)(p + 4);
        }
#pragma unroll
        for (int i = 0; i < 8; ++i) {
            const int kk = c * 8 + i;
            s16x8 af;
#pragma unroll
            for (int j = 0; j < 4; ++j) {
                af[j]     = f2bf(xv[2 * i][j]);
                af[4 + j] = f2bf(xv[2 * i + 1][j]);
            }
            s16x8 b0 = *(const s16x8*)(s0 + kk * 32);
            s16x8 b1 = *(const s16x8*)(s1 + kk * 32);
            a0 = __builtin_amdgcn_mfma_f32_16x16x32_bf16(af, b0, a0, 0, 0, 0);
            a1 = __builtin_amdgcn_mfma_f32_16x16x32_bf16(af, b1, a1, 0, 0, 0);
        }
    }
}

// Per-wave poll of one 128-word chain with observed-min caching: skips entirely
// when a previous poll already proved min >= tgt. On success, wave-min of the
// just-loaded values is cached (skips future polls when producers run ahead).
__device__ __forceinline__ void wave_poll(unsigned int* f, int tgt, int* seen) {
    if (tgt <= 0 || *seen >= tgt) return;
    const int l = threadIdx.x & 63;
    unsigned int* p0 = f + l;
    unsigned int* p1 = f + 64 + l;
    int a, b;
    for (;;) {
        a = (int)__hip_atomic_load(p0, __ATOMIC_RELAXED, __HIP_MEMORY_SCOPE_AGENT);
        b = (int)__hip_atomic_load(p1, __ATOMIC_RELAXED, __HIP_MEMORY_SCOPE_AGENT);
        if (__all((a >= tgt) && (b >= tgt))) break;
        __builtin_amdgcn_s_sleep(1);
    }
    int v = (a < b) ? a : b;                       // wave-min of current flags
#pragma unroll
    for (int off = 32; off; off >>= 1) {
        int w = __shfl_xor(v, off, 64);
        v = (w < v) ? w : v;
    }
    *seen = v;
    asm volatile("" ::: "memory");
}

__global__ void ws_init(unsigned int* p, int n) {
    for (int i = blockIdx.x * blockDim.x + threadIdx.x; i < n; i += gridDim.x * blockDim.x)
        p[i] = 0u;
}

__global__ void __launch_bounds__(THREADS, 1)
lstm_enc(const int* __restrict__ src, const float* __restrict__ Wemb,
         const float* __restrict__ Wih, const float* __restrict__ Whh,
         const float* __restrict__ bih, const float* __restrict__ bhh,
         float* __restrict__ out, bf16* __restrict__ hbuf)
{
    __shared__ __align__(16) bf16 slab[NCOLS][ROWSTRIDE];   // 131,584 B
    __shared__ float bias[NCOLS];

    const int wg    = blockIdx.x;
    const int layer = wg >> 7;
    const int wgl   = wg & 127;
    const int j0    = wgl * UNITS;
    const int tid   = threadIdx.x;
    const int lane  = tid & 63;
    const int wave  = tid >> 6;
    const int m     = lane & 15;
    const int q     = lane >> 4;
    const int kq    = q * 8;
    const int b_a   = wave * 16 + m;           // batch row this lane loads for A

    // ---- weight slab: rows = [i8|f8|g8|o8], K = [W_ih row | W_hh row] ----
    for (int r = 0; r < NCOLS; ++r) {
        int g = r >> 3, u = r & 7;
        size_t grow = (size_t)layer * GATES * HID + (size_t)(g * HID + j0 + u) * HID;
        int k = tid * 8;
        const float* s = (k < HID) ? (Wih + grow + k) : (Whh + grow + (k - HID));
        s16x8 v;
#pragma unroll
        for (int j = 0; j < 8; ++j) v[j] = f2bf(s[j]);
        *(s16x8*)&slab[r][k] = v;
    }
    if (tid < NCOLS) {
        int g = tid >> 3, u = tid & 7;
        int off = layer * GATES + g * HID + j0 + u;
        bias[tid] = bih[off] + bhh[off];
    }
    __syncthreads();                           // slab/bias ready (only barrier)

    bf16* h0 = hbuf;                           // [8][B][H] ring
    bf16* h1 = hbuf + H0_SLOTS * BH;           // [2][B][H] ring
    unsigned int* flags = (unsigned int*)((char*)hbuf + FLAGS_OFF);
    unsigned int* f0 = flags + wave * 128;             // this wave's L0 chain
    unsigned int* f1 = flags + 512 + wave * 128;       // this wave's L1 chain
    unsigned int* myflag = flags + layer * 512 + wave * 128 + wgl;

    // per-lane epilogue constants: unit u = m&7; rows R = wave*16 + q*4 + r
    const int u = m & 7;
    const float b_i = bias[u], b_f = bias[8 + u], b_g = bias[16 + u], b_o = bias[24 + u];
    float c_s[4] = {0.f, 0.f, 0.f, 0.f};
    int seenA = 0, seenB = 0;

    int sv = (layer == 0) ? src[b_a * SEQ] : 0;

    for (int t = 0; t < SEQ; ++t) {
        f32x4 acc0 = {0.f, 0.f, 0.f, 0.f};
        f32x4 acc1 = {0.f, 0.f, 0.f, 0.f};

        if (layer == 0) {
            // embedding x-GEMM: no cross-WG dep, overlaps the recurrence wait
            const float* xF = Wemb + (size_t)sv * HID + kq;
            if (t + 1 < SEQ) sv = src[b_a * SEQ + t + 1];
            gemm_f32c(xF, &slab[m][kq], &slab[16 + m][kq], acc0, acc1);
            wave_poll(f0, t, &seenA);          // own chain: h0[t-1] rows ready
            if (t >= 1)
                gemm_bt(h0 + (size_t)((t - 1) & 7) * BH + b_a * HID + kq,
                        &slab[m][HID + kq], &slab[16 + m][HID + kq], acc0, acc1);
            wave_poll(f1, t - 7, &seenB);      // ring protect (slack 7, mostly skipped)
        } else {
            wave_poll(f0, t + 1, &seenA);      // L0 ahead -> mostly cached/skipped
            gemm_bt(h0 + (size_t)(t & 7) * BH + b_a * HID + kq,
                    &slab[m][kq], &slab[16 + m][kq], acc0, acc1);
            wave_poll(f1, t, &seenB);          // own recurrence (irreducible)
            if (t >= 1)
                gemm_bt(h1 + (size_t)((t - 1) & 1) * BH + b_a * HID + kq,
                        &slab[m][HID + kq], &slab[16 + m][HID + kq], acc0, acc1);
        }

        // ---- in-wave epilogue: gates i/f (cols u,u+8) and g/o (16+u,24+u) sit in
        // lane pair (u, u+8); one shfl_xor(8) pair assembles all 4 gates per lane.
        // Identical f32 values/ordering as the gates-LDS path -> bitwise-same output.
        float hval[4];
#pragma unroll
        for (int r = 0; r < 4; ++r) {
            float p0 = __shfl_xor(acc0[r], 8, 64);
            float p1 = __shfl_xor(acc1[r], 8, 64);
            const bool lo = (m < 8);
            float gi = (lo ? acc0[r] : p0) + b_i;
            float gf = (lo ? p0 : acc0[r]) + b_f;
            float gg = (lo ? acc1[r] : p1) + b_g;
            float go = (lo ? p1 : acc1[r]) + b_o;
            float si = 1.f / (1.f + __expf(-gi));
            float sf = 1.f / (1.f + __expf(-gf));
            float so = 1.f / (1.f + __expf(-go));
            c_s[r] = sf * c_s[r] + si * tanhf(gg);
            hval[r] = so * tanhf(c_s[r]);
        }

        // h ring store (lanes m<8 own the unique copy), write-through to MALL
        bf16* hw = (layer == 0) ? h0 + (size_t)(t & 7) * BH
                                : h1 + (size_t)(t & 1) * BH;
        if (m < 8) {
#pragma unroll
            for (int r = 0; r < 4; ++r) {
                int R = wave * 16 + q * 4 + r;
                __hip_atomic_store((unsigned short*)(hw + (size_t)R * HID + j0 + u),
                                   (unsigned short)f2bf(hval[r]),
                                   __ATOMIC_RELAXED, __HIP_MEMORY_SCOPE_AGENT);
            }
        }
        // per-wave drain + flag post: no barrier, waves fully decoupled
        asm volatile("s_waitcnt vmcnt(0)"); __builtin_amdgcn_sched_barrier(0);
        asm volatile("" ::: "memory");
        if (lane == 0)
            __hip_atomic_store(myflag, (unsigned int)(t + 1),
                               __ATOMIC_RELAXED, __HIP_MEMORY_SCOPE_AGENT);

        // post-flag outputs: off the recurrence critical path
        if (layer == 1 && m < 8) {
#pragma unroll
            for (int r = 0; r < 4; ++r) {
                int R = wave * 16 + q * 4 + r;
                out[((size_t)R * SEQ + t) * HID + j0 + u] = hval[r];
            }
        }
        if (t == SEQ - 1 && m < 8) {
#pragma unroll
            for (int r = 0; r < 4; ++r) {
                int R = wave * 16 + q * 4 + r;
                size_t o = ((size_t)layer * BATCH + R) * HID + j0 + u;
                out[OUT_HN + o] = hval[r];
                out[OUT_CN + o] = c_s[r];
            }
        }
    }
}

extern "C" void kernel_launch(void* const* d_in, const int* in_sizes, int n_in,
                              void* d_out, int out_size, void* d_ws, size_t ws_size,
                              hipStream_t stream) {
    const int*   src  = (const int*)d_in[0];
    const float* emb  = (const float*)d_in[1];
    const float* W_ih = (const float*)d_in[2];
    const float* W_hh = (const float*)d_in[3];
    const float* b_ih = (const float*)d_in[4];
    const float* b_hh = (const float*)d_in[5];
    float* out  = (float*)d_out;
    bf16*  hbuf = (bf16*)d_ws;                 // rings + 4 KB flags

    // zero the 1024 per-(layer,wave,wg) flag words (ws re-poisoned each replay;
    // rings need no init: every slot is written before it is ever read)
    unsigned int* wsp = (unsigned int*)((char*)d_ws + FLAGS_OFF);
    ws_init<<<4, 256, 0, stream>>>(wsp, 1024);

    void* args[] = {&src, &emb, &W_ih, &W_hh, &b_ih, &b_hh, &out, &hbuf};
    hipLaunchCooperativeKernel((void*)lstm_enc, dim3(NWG), dim3(THREADS),
                               args, 0, stream);
}